// Round 1
// baseline (9880.066 us; speedup 1.0000x reference)
//
#include <hip/hip_runtime.h>

typedef __attribute__((ext_vector_type(8))) short short8;
typedef __attribute__((ext_vector_type(4))) float f32x4;
typedef __attribute__((ext_vector_type(4))) unsigned short u16x4;

#define T_TOT 1024
#define NBATCH 64
#define NIN 512
#define NHID 1024
#define NG 4096            // 4*NHID
#define BH 65536           // NBATCH*NHID
#define OUT_MAIN 67108864ull  // T_TOT*BH

__device__ __forceinline__ unsigned short f2bf(float f) {
  unsigned int u = __builtin_bit_cast(unsigned int, f);
  u += 0x7fffu + ((u >> 16) & 1u);
  return (unsigned short)(u >> 16);
}
__device__ __forceinline__ float sigf(float x) { return 1.0f / (1.0f + __expf(-x)); }
// saturation-safe tanh (no inf/inf)
__device__ __forceinline__ float tanh_f(float x) { return 1.0f - 2.0f / (1.0f + __expf(2.0f * x)); }

// Device-coherent (cross-XCD) 16B load / 8B store: sc0 sc1 bypass L1+L2 and
// hit the coherence point directly. These replace fence-based coherence for
// the h_state exchange — the ONLY racing data in the recurrence.
__device__ __forceinline__ short8 ldg_coh16(const unsigned short* p) {
  short8 r;
  asm volatile("global_load_dwordx4 %0, %1, off sc0 sc1"
               : "=v"(r) : "v"(p) : "memory");
  return r;
}
__device__ __forceinline__ void stg_coh8(unsigned short* p, u16x4 v) {
  asm volatile("global_store_dwordx2 %0, %1, off sc0 sc1"
               :: "v"(p), "v"(v) : "memory");
}

// ---------------------------------------------------------------------------
// Prep: cast weights to bf16, fold biases, init h/c state, zero barrier.
// ---------------------------------------------------------------------------
__global__ void __launch_bounds__(256) prep_kernel(
    const float* __restrict__ w_ih, const float* __restrict__ w_hh,
    const float* __restrict__ b_ih, const float* __restrict__ b_hh,
    const float* __restrict__ h0, const float* __restrict__ c0,
    unsigned short* __restrict__ w_ihb, unsigned short* __restrict__ w_hhb,
    float* __restrict__ bsum, unsigned short* __restrict__ h_state,
    float* __restrict__ c_ws, unsigned int* __restrict__ bar)
{
  int tid = blockIdx.x * blockDim.x + threadIdx.x;
  int stride = gridDim.x * blockDim.x;
  if (tid == 0) *bar = 0u;
  for (int i = tid; i < NG * NHID; i += stride) w_hhb[i] = f2bf(w_hh[i]);
  for (int i = tid; i < NG * NIN; i += stride) w_ihb[i] = f2bf(w_ih[i]);
  for (int i = tid; i < NG; i += stride) bsum[i] = b_ih[i] + b_hh[i];
  for (int i = tid; i < BH; i += stride) { h_state[i] = f2bf(h0[i]); c_ws[i] = c0[i]; }
}

// ---------------------------------------------------------------------------
// x_proj GEMM: xp[row][g] = sum_i x[row][i] * w_ih[g][i]   (fp32 out, bias later)
// 128x128 tile, K=512 in 8 k-blocks of 64. bf16 MFMA 16x16x32.
// ---------------------------------------------------------------------------
__global__ void __launch_bounds__(256) xp_gemm(
    const float* __restrict__ x,              // [M][512] chunk base
    const unsigned short* __restrict__ w_ihb, // [4096][512] bf16
    float* __restrict__ xp)                   // [M][4096] fp32
{
  __shared__ unsigned short As[128][72];
  __shared__ unsigned short Bs[128][72];
  const int tid = threadIdx.x;
  const int lane = tid & 63;
  const int wave = tid >> 6;
  const int l15 = lane & 15, l4 = lane >> 4;
  const int wy = wave >> 1, wx = wave & 1;   // 2x2 waves over 128x128
  const int row0 = blockIdx.x * 128;
  const int col0 = blockIdx.y * 128;

  f32x4 acc[4][4];
#pragma unroll
  for (int mt = 0; mt < 4; ++mt)
#pragma unroll
    for (int nt = 0; nt < 4; ++nt) acc[mt][nt] = (f32x4){0.f, 0.f, 0.f, 0.f};

  for (int kb = 0; kb < 8; ++kb) {
    const int k0 = kb * 64;
#pragma unroll
    for (int i = 0; i < 4; ++i) {
      int idx = tid + 256 * i;
      int r = idx >> 3, kc = (idx & 7) * 8;
      const float* src = x + (size_t)(row0 + r) * NIN + k0 + kc;
      float4 f0 = *(const float4*)src;
      float4 f1 = *(const float4*)(src + 4);
      short8 v;
      v[0] = (short)f2bf(f0.x); v[1] = (short)f2bf(f0.y);
      v[2] = (short)f2bf(f0.z); v[3] = (short)f2bf(f0.w);
      v[4] = (short)f2bf(f1.x); v[5] = (short)f2bf(f1.y);
      v[6] = (short)f2bf(f1.z); v[7] = (short)f2bf(f1.w);
      *(short8*)&As[r][kc] = v;
    }
#pragma unroll
    for (int i = 0; i < 4; ++i) {
      int idx = tid + 256 * i;
      int r = idx >> 3, kc = (idx & 7) * 8;
      short8 v = *(const short8*)(w_ihb + (size_t)(col0 + r) * NIN + k0 + kc);
      *(short8*)&Bs[r][kc] = v;
    }
    __syncthreads();
#pragma unroll
    for (int kk = 0; kk < 2; ++kk) {
      const int kl = kk * 32 + l4 * 8;
      short8 a[4], b[4];
#pragma unroll
      for (int mt = 0; mt < 4; ++mt) a[mt] = *(const short8*)&As[wy * 64 + mt * 16 + l15][kl];
#pragma unroll
      for (int nt = 0; nt < 4; ++nt) b[nt] = *(const short8*)&Bs[wx * 64 + nt * 16 + l15][kl];
#pragma unroll
      for (int mt = 0; mt < 4; ++mt)
#pragma unroll
        for (int nt = 0; nt < 4; ++nt)
          acc[mt][nt] = __builtin_amdgcn_mfma_f32_16x16x32_bf16(a[mt], b[nt], acc[mt][nt], 0, 0, 0);
    }
    __syncthreads();
  }
  // C/D layout: col=lane&15, row=(lane>>4)*4+reg
#pragma unroll
  for (int mt = 0; mt < 4; ++mt)
#pragma unroll
    for (int nt = 0; nt < 4; ++nt)
#pragma unroll
      for (int j = 0; j < 4; ++j) {
        int r = row0 + wy * 64 + mt * 16 + l4 * 4 + j;
        int c = col0 + wx * 64 + nt * 16 + l15;
        xp[(size_t)r * NG + c] = acc[mt][nt][j];
      }
}

// ---------------------------------------------------------------------------
// Fence-FREE grid barrier. Correctness protocol (gfx940+ memory model):
//  - producers store h via sc0/sc1 write-through stores (visible at the
//    coherence point once vmcnt retires them),
//  - each wave drains its own stores (s_waitcnt vmcnt(0)) before arriving,
//  - thread0 does a relaxed agent-scope atomic arrive + spins relaxed,
//  - consumers read h via sc0/sc1 loads (bypass stale L1/L2).
// No buffer_wbl2 / buffer_inv per step: 'out' is write-only (kernel-end
// writeback covers it), xp/w_hh/bias are launch-invariant, c is in regs.
// ---------------------------------------------------------------------------
__device__ __forceinline__ void gbar_nf(unsigned int* bar, unsigned int target) {
  asm volatile("s_waitcnt vmcnt(0)" ::: "memory");   // own h stores globally visible
  __syncthreads();                                   // whole block's stores visible
  if (threadIdx.x == 0) {
    __hip_atomic_fetch_add(bar, 1u, __ATOMIC_RELAXED, __HIP_MEMORY_SCOPE_AGENT);
    while (__hip_atomic_load(bar, __ATOMIC_RELAXED, __HIP_MEMORY_SCOPE_AGENT) < target) {
      __builtin_amdgcn_s_sleep(1);
    }
  }
  __syncthreads();
}

// ---------------------------------------------------------------------------
// Persistent recurrence. 64 blocks x 256 thr. Block owns 16 h-cols; wave w
// owns K in [256w,256w+256); w_hh fragments live in registers for all steps.
// h fragment loads are depth-2 prefetched with counted vmcnt waits:
//   prologue issues A(0),A(1); iter kk issues A(kk+2) then waits vmcnt(8)
//   (a(kk) has >=8 younger vmem ops -> in-order completion guarantees it).
//   Counted waits stay correct under any compiler-interleaved loads: extra
//   ops only make the wait stricter, never looser.
// ---------------------------------------------------------------------------
__global__ void __launch_bounds__(256, 1) lstm_rec(
    const float* __restrict__ xp,            // [Tc][64][4096] fp32
    const unsigned short* __restrict__ w_hhb,// [4096][1024] bf16
    const float* __restrict__ bsum,          // [4096]
    unsigned short* __restrict__ h_state,    // [2][64][1024] bf16 ping-pong
    float* __restrict__ c_ws,                // [64][1024]
    float* __restrict__ out,                 // d_out
    unsigned int* __restrict__ bar,
    int t0, int Tc)
{
  __shared__ float part[4][64][68];          // [wave][row][gatecol] padded +4
  const int tid = threadIdx.x;
  const int lane = tid & 63;
  const int wave = tid >> 6;
  const int l15 = lane & 15;
  const int l4 = lane >> 4;
  const int col0 = blockIdx.x * 16;

  // elementwise ownership: 1 row x 4 contiguous cols
  const int er = tid >> 2;          // batch row 0..63
  const int ec = (tid & 3) * 4;     // col group within the block's 16

  f32x4 c_reg = *(const f32x4*)&c_ws[er * NHID + col0 + ec];
  f32x4 bias[4];
#pragma unroll
  for (int q = 0; q < 4; ++q) bias[q] = *(const f32x4*)&bsum[q * NHID + col0 + ec];

  // Preload B fragments (w_hh rows for this block's 64 gate cols, this wave's K)
  short8 breg[4][8];
#pragma unroll
  for (int q = 0; q < 4; ++q)
#pragma unroll
    for (int kk = 0; kk < 8; ++kk) {
      const unsigned short* p =
          w_hhb + (size_t)(q * NHID + col0 + l15) * NHID + wave * 256 + kk * 32 + l4 * 8;
      breg[q][kk] = *(const short8*)p;
    }

  for (int tt = 0; tt < Tc; ++tt) {
    const int t = t0 + tt;
    const unsigned short* h = h_state + (size_t)(t & 1) * BH;
    // per-thread base for A-fragment addresses:
    //   addr(mt,kk) = h + (mt*16+l15)*NHID + wave*256 + kk*32 + l4*8
    const unsigned short* hbase = h + (size_t)l15 * NHID + wave * 256 + l4 * 8;

    // xp for this thread's cols: independent of h, issue early (plain/cached)
    f32x4 xv[4];
#pragma unroll
    for (int q = 0; q < 4; ++q)
      xv[q] = *(const f32x4*)(xp + ((size_t)tt * NBATCH + er) * NG + q * NHID + col0 + ec);

    f32x4 acc[4][4];
#pragma unroll
    for (int mt = 0; mt < 4; ++mt)
#pragma unroll
      for (int q = 0; q < 4; ++q) acc[mt][q] = (f32x4){0.f, 0.f, 0.f, 0.f};

    // depth-2 prefetch pipeline over the 8 K-subtiles
    short8 abuf[3][4];
#pragma unroll
    for (int mt = 0; mt < 4; ++mt)
      abuf[0][mt] = ldg_coh16(hbase + mt * 16 * NHID);
#pragma unroll
    for (int mt = 0; mt < 4; ++mt)
      abuf[1][mt] = ldg_coh16(hbase + mt * 16 * NHID + 32);

#pragma unroll
    for (int kk = 0; kk < 8; ++kk) {
      if (kk < 6) {
#pragma unroll
        for (int mt = 0; mt < 4; ++mt)
          abuf[(kk + 2) % 3][mt] = ldg_coh16(hbase + mt * 16 * NHID + (kk + 2) * 32);
        asm volatile("s_waitcnt vmcnt(8)" ::: "memory");
      } else if (kk == 6) {
        asm volatile("s_waitcnt vmcnt(4)" ::: "memory");
      } else {
        asm volatile("s_waitcnt vmcnt(0)" ::: "memory");
      }
      __builtin_amdgcn_sched_barrier(0);   // keep MFMAs below the waitcnt
#pragma unroll
      for (int mt = 0; mt < 4; ++mt)
#pragma unroll
        for (int q = 0; q < 4; ++q)
          acc[mt][q] = __builtin_amdgcn_mfma_f32_16x16x32_bf16(
              abuf[kk % 3][mt], breg[q][kk], acc[mt][q], 0, 0, 0);
    }

    // partial K-sums to LDS (C/D layout: col=lane&15, row=(lane>>4)*4+reg)
#pragma unroll
    for (int mt = 0; mt < 4; ++mt)
#pragma unroll
      for (int q = 0; q < 4; ++q)
#pragma unroll
        for (int j = 0; j < 4; ++j)
          part[wave][mt * 16 + l4 * 4 + j][q * 16 + l15] = acc[mt][q][j];
    __syncthreads();

    // reduce across waves (vectorized) + gate fusion + state update
    f32x4 g[4];
#pragma unroll
    for (int q = 0; q < 4; ++q) {
      f32x4 s = *(const f32x4*)&part[0][er][q * 16 + ec];
      s += *(const f32x4*)&part[1][er][q * 16 + ec];
      s += *(const f32x4*)&part[2][er][q * 16 + ec];
      s += *(const f32x4*)&part[3][er][q * 16 + ec];
      g[q] = s + bias[q] + xv[q];
    }
    f32x4 hv4;
    u16x4 hb4;
#pragma unroll
    for (int j = 0; j < 4; ++j) {
      float ig = sigf(g[0][j]);
      float fg = sigf(g[1][j]);
      float gg = tanh_f(g[2][j]);
      float og = sigf(g[3][j]);
      float c = fg * c_reg[j] + ig * gg;
      c_reg[j] = c;
      float hv = og * tanh_f(c);
      hv4[j] = hv;
      hb4[j] = f2bf(hv);
    }
    *(f32x4*)&out[(size_t)t * BH + (size_t)er * NHID + col0 + ec] = hv4;  // plain
    // coherent write-through h for next step's cross-XCD readers
    stg_coh8(h_state + (size_t)((t + 1) & 1) * BH + er * NHID + col0 + ec, hb4);
    if (t == T_TOT - 1) {
      *(f32x4*)&out[OUT_MAIN + (size_t)er * NHID + col0 + ec] = hv4;          // h_f
      *(f32x4*)&out[OUT_MAIN + BH + (size_t)er * NHID + col0 + ec] = c_reg;   // c_f
    }

    gbar_nf(bar, (unsigned int)(t + 1) * 64u);
  }

  // carry c across chunk launches (plain; kernel-end writeback)
  *(f32x4*)&c_ws[er * NHID + col0 + ec] = c_reg;
}

// ---------------------------------------------------------------------------
extern "C" void kernel_launch(void* const* d_in, const int* in_sizes, int n_in,
                              void* d_out, int out_size, void* d_ws, size_t ws_size,
                              hipStream_t stream) {
  const float* x   = (const float*)d_in[0];
  const float* h0  = (const float*)d_in[1];
  const float* c0  = (const float*)d_in[2];
  const float* wih = (const float*)d_in[3];
  const float* whh = (const float*)d_in[4];
  const float* bih = (const float*)d_in[5];
  const float* bhh = (const float*)d_in[6];
  float* out = (float*)d_out;

  char* base = (char*)d_ws;
  size_t off = 0;
  auto alloc = [&](size_t bytes) {
    char* r = base + off;
    off += (bytes + 255) & ~(size_t)255;
    return r;
  };
  unsigned short* w_hhb   = (unsigned short*)alloc((size_t)NG * NHID * 2);
  unsigned short* w_ihb   = (unsigned short*)alloc((size_t)NG * NIN * 2);
  float*          bsum    = (float*)alloc((size_t)NG * 4);
  unsigned short* h_state = (unsigned short*)alloc(2ull * BH * 2);
  float*          c_ws    = (float*)alloc((size_t)BH * 4);
  unsigned int*   bar     = (unsigned int*)alloc(256);

  // largest power-of-2 timestep chunk whose fp32 xp buffer fits in ws
  int Tc = T_TOT;
  while (Tc > 2 && off + (size_t)Tc * NBATCH * NG * 4 > ws_size) Tc >>= 1;
  float* xp = (float*)alloc((size_t)Tc * NBATCH * NG * 4);

  prep_kernel<<<dim3(512), dim3(256), 0, stream>>>(
      wih, whh, bih, bhh, h0, c0, w_ihb, w_hhb, bsum, h_state, c_ws, bar);

  for (int t0 = 0; t0 < T_TOT; t0 += Tc) {
    xp_gemm<<<dim3(Tc / 2, 32), dim3(256), 0, stream>>>(
        x + (size_t)t0 * NBATCH * NIN, w_ihb, xp);
    lstm_rec<<<dim3(64), dim3(256), 0, stream>>>(
        xp, w_hhb, bsum, h_state, c_ws, out, bar, t0, Tc);
  }
}

// Round 2
// 8871.913 us; speedup vs baseline: 1.1136x; 1.1136x over previous
//
#include <hip/hip_runtime.h>

typedef __attribute__((ext_vector_type(8))) short short8;
typedef __attribute__((ext_vector_type(4))) float f32x4;
typedef __attribute__((ext_vector_type(4))) unsigned short u16x4;

#define T_TOT 1024
#define NBATCH 64
#define NIN 512
#define NHID 1024
#define NG 4096            // 4*NHID
#define BH 65536           // NBATCH*NHID
#define OUT_MAIN 67108864ull  // T_TOT*BH

__device__ __forceinline__ unsigned short f2bf(float f) {
  unsigned int u = __builtin_bit_cast(unsigned int, f);
  u += 0x7fffu + ((u >> 16) & 1u);
  return (unsigned short)(u >> 16);
}
__device__ __forceinline__ float sigf(float x) { return 1.0f / (1.0f + __expf(-x)); }
// saturation-safe tanh (no inf/inf)
__device__ __forceinline__ float tanh_f(float x) { return 1.0f - 2.0f / (1.0f + __expf(2.0f * x)); }

// Device-coherent (cross-XCD) accesses: sc0 sc1 bypass L1+L2, hit the
// coherence point directly. Used for ALL racing data (h_state + flags).
template<int OFS>
__device__ __forceinline__ short8 ldg_coh16_o(const unsigned short* p) {
  short8 r;
  asm volatile("global_load_dwordx4 %0, %1, off offset:%2 sc0 sc1"
               : "=v"(r) : "v"(p), "i"(OFS) : "memory");
  return r;
}
__device__ __forceinline__ void stg_coh8(unsigned short* p, u16x4 v) {
  asm volatile("global_store_dwordx2 %0, %1, off sc0 sc1"
               :: "v"(p), "v"(v) : "memory");
}
__device__ __forceinline__ unsigned int ld_coh32(const unsigned int* p) {
  unsigned int r;
  asm volatile("global_load_dword %0, %1, off sc0 sc1\n\ts_waitcnt vmcnt(0)"
               : "=v"(r) : "v"(p) : "memory");
  return r;
}
__device__ __forceinline__ void st_coh32(unsigned int* p, unsigned int v) {
  asm volatile("global_store_dword %0, %1, off sc0 sc1" :: "v"(p), "v"(v) : "memory");
}

// ---------------------------------------------------------------------------
// Prep: cast weights to bf16, fold biases, init h/c state, zero flags.
// ---------------------------------------------------------------------------
__global__ void __launch_bounds__(256) prep_kernel(
    const float* __restrict__ w_ih, const float* __restrict__ w_hh,
    const float* __restrict__ b_ih, const float* __restrict__ b_hh,
    const float* __restrict__ h0, const float* __restrict__ c0,
    unsigned short* __restrict__ w_ihb, unsigned short* __restrict__ w_hhb,
    float* __restrict__ bsum, unsigned short* __restrict__ h_state,
    float* __restrict__ c_ws, unsigned int* __restrict__ flags)
{
  int tid = blockIdx.x * blockDim.x + threadIdx.x;
  int stride = gridDim.x * blockDim.x;
  for (int i = tid; i < 256; i += stride) flags[i] = 0u;
  for (int i = tid; i < NG * NHID; i += stride) w_hhb[i] = f2bf(w_hh[i]);
  for (int i = tid; i < NG * NIN; i += stride) w_ihb[i] = f2bf(w_ih[i]);
  for (int i = tid; i < NG; i += stride) bsum[i] = b_ih[i] + b_hh[i];
  for (int i = tid; i < BH; i += stride) { h_state[i] = f2bf(h0[i]); c_ws[i] = c0[i]; }
}

// ---------------------------------------------------------------------------
// x_proj GEMM: xp[row][g] = sum_i x[row][i] * w_ih[g][i]   (fp32 out, bias later)
// 128x128 tile, K=512 in 8 k-blocks of 64. bf16 MFMA 16x16x32.
// ---------------------------------------------------------------------------
__global__ void __launch_bounds__(256) xp_gemm(
    const float* __restrict__ x,              // [M][512] chunk base
    const unsigned short* __restrict__ w_ihb, // [4096][512] bf16
    float* __restrict__ xp)                   // [M][4096] fp32
{
  __shared__ unsigned short As[128][72];
  __shared__ unsigned short Bs[128][72];
  const int tid = threadIdx.x;
  const int lane = tid & 63;
  const int wave = tid >> 6;
  const int l15 = lane & 15, l4 = lane >> 4;
  const int wy = wave >> 1, wx = wave & 1;   // 2x2 waves over 128x128
  const int row0 = blockIdx.x * 128;
  const int col0 = blockIdx.y * 128;

  f32x4 acc[4][4];
#pragma unroll
  for (int mt = 0; mt < 4; ++mt)
#pragma unroll
    for (int nt = 0; nt < 4; ++nt) acc[mt][nt] = (f32x4){0.f, 0.f, 0.f, 0.f};

  for (int kb = 0; kb < 8; ++kb) {
    const int k0 = kb * 64;
#pragma unroll
    for (int i = 0; i < 4; ++i) {
      int idx = tid + 256 * i;
      int r = idx >> 3, kc = (idx & 7) * 8;
      const float* src = x + (size_t)(row0 + r) * NIN + k0 + kc;
      float4 f0 = *(const float4*)src;
      float4 f1 = *(const float4*)(src + 4);
      short8 v;
      v[0] = (short)f2bf(f0.x); v[1] = (short)f2bf(f0.y);
      v[2] = (short)f2bf(f0.z); v[3] = (short)f2bf(f0.w);
      v[4] = (short)f2bf(f1.x); v[5] = (short)f2bf(f1.y);
      v[6] = (short)f2bf(f1.z); v[7] = (short)f2bf(f1.w);
      *(short8*)&As[r][kc] = v;
    }
#pragma unroll
    for (int i = 0; i < 4; ++i) {
      int idx = tid + 256 * i;
      int r = idx >> 3, kc = (idx & 7) * 8;
      short8 v = *(const short8*)(w_ihb + (size_t)(col0 + r) * NIN + k0 + kc);
      *(short8*)&Bs[r][kc] = v;
    }
    __syncthreads();
#pragma unroll
    for (int kk = 0; kk < 2; ++kk) {
      const int kl = kk * 32 + l4 * 8;
      short8 a[4], b[4];
#pragma unroll
      for (int mt = 0; mt < 4; ++mt) a[mt] = *(const short8*)&As[wy * 64 + mt * 16 + l15][kl];
#pragma unroll
      for (int nt = 0; nt < 4; ++nt) b[nt] = *(const short8*)&Bs[wx * 64 + nt * 16 + l15][kl];
#pragma unroll
      for (int mt = 0; mt < 4; ++mt)
#pragma unroll
        for (int nt = 0; nt < 4; ++nt)
          acc[mt][nt] = __builtin_amdgcn_mfma_f32_16x16x32_bf16(a[mt], b[nt], acc[mt][nt], 0, 0, 0);
    }
    __syncthreads();
  }
  // C/D layout: col=lane&15, row=(lane>>4)*4+reg
#pragma unroll
  for (int mt = 0; mt < 4; ++mt)
#pragma unroll
    for (int nt = 0; nt < 4; ++nt)
#pragma unroll
      for (int j = 0; j < 4; ++j) {
        int r = row0 + wy * 64 + mt * 16 + l4 * 4 + j;
        int c = col0 + wx * 64 + nt * 16 + l15;
        xp[(size_t)r * NG + c] = acc[mt][nt][j];
      }
}

// ---------------------------------------------------------------------------
// K-group helpers for the recurrence: issue all 32 h-fragment loads up front,
// then drain with counted vmcnt per 4-load group. Counts are exact because the
// flag-poll exits with vmcnt==0; any compiler-inserted vmem ops are younger
// and only make the waits stricter.
// ---------------------------------------------------------------------------
template<int KK>
__device__ __forceinline__ void loadk(short8 (&abuf)[8][4],
    const unsigned short* hb0, const unsigned short* hb1,
    const unsigned short* hb2, const unsigned short* hb3) {
  abuf[KK][0] = ldg_coh16_o<KK * 64>(hb0);
  abuf[KK][1] = ldg_coh16_o<KK * 64>(hb1);
  abuf[KK][2] = ldg_coh16_o<KK * 64>(hb2);
  abuf[KK][3] = ldg_coh16_o<KK * 64>(hb3);
}
template<int KK>
__device__ __forceinline__ void kgroup(short8 (&abuf)[8][4],
    const short8 (&breg)[4][8], f32x4 (&acc)[4][4]) {
  asm volatile("s_waitcnt vmcnt(%0)" :: "i"(28 - 4 * KK) : "memory");
  __builtin_amdgcn_sched_barrier(0);   // keep MFMAs below the waitcnt (rule #18)
#pragma unroll
  for (int mt = 0; mt < 4; ++mt)
#pragma unroll
    for (int q = 0; q < 4; ++q)
      acc[mt][q] = __builtin_amdgcn_mfma_f32_16x16x32_bf16(
          abuf[KK][mt], breg[q][KK], acc[mt][q], 0, 0, 0);
}

// ---------------------------------------------------------------------------
// Persistent recurrence, per-wave flag synchronization (no atomic RMW, no
// fences). flags[b*4+w] = t+1 published by wave w of block b after its h
// stores drain (vmcnt(0)). Consumer wave w needs K in [256w,256w+256) =
// cols of blocks 16w..16w+15 -> its 64 lanes poll those blocks' 4 wave-flags
// in ONE parallel coherent load per round, exit on __all(v >= t).
// Safety of the partial barrier: stores happen after the pre-reduce
// __syncthreads, which requires all 4 waves' waits (union = ALL 64 blocks
// at flag >= t) -> no block can overwrite a ping-pong buffer another block
// is still reading. A second __syncthreads after the reduce protects the
// LDS 'part' buffer across steps.
// ---------------------------------------------------------------------------
__global__ void __launch_bounds__(256, 1) lstm_rec(
    const float* __restrict__ xp,            // [Tc][64][4096] fp32
    const unsigned short* __restrict__ w_hhb,// [4096][1024] bf16
    const float* __restrict__ bsum,          // [4096]
    unsigned short* __restrict__ h_state,    // [2][64][1024] bf16 ping-pong
    float* __restrict__ c_ws,                // [64][1024]
    float* __restrict__ out,                 // d_out
    unsigned int* __restrict__ flags,        // [64 blocks][4 waves]
    int t0, int Tc)
{
  __shared__ float part[4][64][68];          // [wave][row][gatecol] padded +4
  const int tid = threadIdx.x;
  const int lane = tid & 63;
  const int wave = tid >> 6;
  const int l15 = lane & 15;
  const int l4 = lane >> 4;
  const int col0 = blockIdx.x * 16;

  // elementwise ownership: 1 row x 4 contiguous cols
  const int er = tid >> 2;          // batch row 0..63
  const int ec = (tid & 3) * 4;     // col group within the block's 16

  // flag this wave publishes, and the producer flag its lane monitors
  unsigned int* myflag = flags + (blockIdx.x * 4 + wave);
  const unsigned int* pflag = flags + ((wave * 16 + (lane >> 2)) * 4 + (lane & 3));

  f32x4 c_reg = *(const f32x4*)&c_ws[er * NHID + col0 + ec];
  f32x4 bias[4];
#pragma unroll
  for (int q = 0; q < 4; ++q) bias[q] = *(const f32x4*)&bsum[q * NHID + col0 + ec];

  // Preload B fragments (w_hh rows for this block's 64 gate cols, this wave's K)
  short8 breg[4][8];
#pragma unroll
  for (int q = 0; q < 4; ++q)
#pragma unroll
    for (int kk = 0; kk < 8; ++kk) {
      const unsigned short* p =
          w_hhb + (size_t)(q * NHID + col0 + l15) * NHID + wave * 256 + kk * 32 + l4 * 8;
      breg[q][kk] = *(const short8*)p;
    }

  for (int tt = 0; tt < Tc; ++tt) {
    const int t = t0 + tt;
    const unsigned short* h = h_state + (size_t)(t & 1) * BH;
    // per-thread A-fragment bases: addr(mt,kk) = hb<mt> + kk*64 bytes
    const unsigned short* hbase = h + (size_t)l15 * NHID + wave * 256 + l4 * 8;
    const unsigned short* hb0 = hbase;
    const unsigned short* hb1 = hbase + 16 * NHID;
    const unsigned short* hb2 = hbase + 32 * NHID;
    const unsigned short* hb3 = hbase + 48 * NHID;

    // xp for this thread's cols: independent of h/flags, issue before the poll
    f32x4 xv[4];
#pragma unroll
    for (int q = 0; q < 4; ++q)
      xv[q] = *(const f32x4*)(xp + ((size_t)tt * NBATCH + er) * NG + q * NHID + col0 + ec);

    // wait for THIS wave's 16 producer blocks (64 wave-flags, one per lane)
    for (;;) {
      unsigned int v = ld_coh32(pflag);
      if (__all((int)(v >= (unsigned int)t))) break;
      __builtin_amdgcn_s_sleep(1);
    }
    // vmcnt == 0 here (ld_coh32 drains)

    f32x4 acc[4][4];
#pragma unroll
    for (int mt = 0; mt < 4; ++mt)
#pragma unroll
      for (int q = 0; q < 4; ++q) acc[mt][q] = (f32x4){0.f, 0.f, 0.f, 0.f};

    // issue ALL 32 A-fragment loads, then drain per-group with counted vmcnt
    short8 abuf[8][4];
    loadk<0>(abuf, hb0, hb1, hb2, hb3);
    loadk<1>(abuf, hb0, hb1, hb2, hb3);
    loadk<2>(abuf, hb0, hb1, hb2, hb3);
    loadk<3>(abuf, hb0, hb1, hb2, hb3);
    loadk<4>(abuf, hb0, hb1, hb2, hb3);
    loadk<5>(abuf, hb0, hb1, hb2, hb3);
    loadk<6>(abuf, hb0, hb1, hb2, hb3);
    loadk<7>(abuf, hb0, hb1, hb2, hb3);

    kgroup<0>(abuf, breg, acc);
    kgroup<1>(abuf, breg, acc);
    kgroup<2>(abuf, breg, acc);
    kgroup<3>(abuf, breg, acc);
    kgroup<4>(abuf, breg, acc);
    kgroup<5>(abuf, breg, acc);
    kgroup<6>(abuf, breg, acc);
    kgroup<7>(abuf, breg, acc);

    // partial K-sums to LDS (C/D layout: col=lane&15, row=(lane>>4)*4+reg)
#pragma unroll
    for (int mt = 0; mt < 4; ++mt)
#pragma unroll
      for (int q = 0; q < 4; ++q)
#pragma unroll
        for (int j = 0; j < 4; ++j)
          part[wave][mt * 16 + l4 * 4 + j][q * 16 + l15] = acc[mt][q][j];
    __syncthreads();

    // reduce across waves (vectorized)
    f32x4 g[4];
#pragma unroll
    for (int q = 0; q < 4; ++q) {
      f32x4 s = *(const f32x4*)&part[0][er][q * 16 + ec];
      s += *(const f32x4*)&part[1][er][q * 16 + ec];
      s += *(const f32x4*)&part[2][er][q * 16 + ec];
      s += *(const f32x4*)&part[3][er][q * 16 + ec];
      g[q] = s + bias[q] + xv[q];
    }
    __syncthreads();   // part reads done; next step's part writes may proceed

    // gate fusion + state update
    f32x4 hv4;
    u16x4 hb4;
#pragma unroll
    for (int j = 0; j < 4; ++j) {
      float ig = sigf(g[0][j]);
      float fg = sigf(g[1][j]);
      float gg = tanh_f(g[2][j]);
      float og = sigf(g[3][j]);
      float c = fg * c_reg[j] + ig * gg;
      c_reg[j] = c;
      float hv = og * tanh_f(c);
      hv4[j] = hv;
      hb4[j] = f2bf(hv);
    }
    // coherent write-through h for next step's cross-XCD readers, then publish
    stg_coh8(h_state + (size_t)((t + 1) & 1) * BH + er * NHID + col0 + ec, hb4);
    asm volatile("s_waitcnt vmcnt(0)" ::: "memory");   // wave's h stores visible
    if (lane == 0) st_coh32(myflag, (unsigned int)(t + 1));

    // off-critical-path stores (plain; kernel-end writeback covers them)
    *(f32x4*)&out[(size_t)t * BH + (size_t)er * NHID + col0 + ec] = hv4;
    if (t == T_TOT - 1) {
      *(f32x4*)&out[OUT_MAIN + (size_t)er * NHID + col0 + ec] = hv4;          // h_f
      *(f32x4*)&out[OUT_MAIN + BH + (size_t)er * NHID + col0 + ec] = c_reg;   // c_f
    }
  }

  // carry c across chunk launches (plain; kernel-end writeback)
  *(f32x4*)&c_ws[er * NHID + col0 + ec] = c_reg;
}

// ---------------------------------------------------------------------------
extern "C" void kernel_launch(void* const* d_in, const int* in_sizes, int n_in,
                              void* d_out, int out_size, void* d_ws, size_t ws_size,
                              hipStream_t stream) {
  const float* x   = (const float*)d_in[0];
  const float* h0  = (const float*)d_in[1];
  const float* c0  = (const float*)d_in[2];
  const float* wih = (const float*)d_in[3];
  const float* whh = (const float*)d_in[4];
  const float* bih = (const float*)d_in[5];
  const float* bhh = (const float*)d_in[6];
  float* out = (float*)d_out;

  char* base = (char*)d_ws;
  size_t off = 0;
  auto alloc = [&](size_t bytes) {
    char* r = base + off;
    off += (bytes + 255) & ~(size_t)255;
    return r;
  };
  unsigned short* w_hhb   = (unsigned short*)alloc((size_t)NG * NHID * 2);
  unsigned short* w_ihb   = (unsigned short*)alloc((size_t)NG * NIN * 2);
  float*          bsum    = (float*)alloc((size_t)NG * 4);
  unsigned short* h_state = (unsigned short*)alloc(2ull * BH * 2);
  float*          c_ws    = (float*)alloc((size_t)BH * 4);
  unsigned int*   flags   = (unsigned int*)alloc(1024);

  // largest power-of-2 timestep chunk whose fp32 xp buffer fits in ws
  int Tc = T_TOT;
  while (Tc > 2 && off + (size_t)Tc * NBATCH * NG * 4 > ws_size) Tc >>= 1;
  float* xp = (float*)alloc((size_t)Tc * NBATCH * NG * 4);

  prep_kernel<<<dim3(512), dim3(256), 0, stream>>>(
      wih, whh, bih, bhh, h0, c0, w_ihb, w_hhb, bsum, h_state, c_ws, flags);

  for (int t0 = 0; t0 < T_TOT; t0 += Tc) {
    xp_gemm<<<dim3(Tc / 2, 32), dim3(256), 0, stream>>>(
        x + (size_t)t0 * NBATCH * NIN, w_ihb, xp);
    lstm_rec<<<dim3(64), dim3(256), 0, stream>>>(
        xp, w_hhb, bsum, h_state, c_ws, out, flags, t0, Tc);
  }
}